// Round 1
// baseline (2655.423 us; speedup 1.0000x reference)
//
#include <hip/hip_runtime.h>
#include <hip/hip_bf16.h>
#include <math.h>

#define BB 32
#define NN 24564
#define CC 81
#define CM1 80
#define KK 100
#define CAP 512
#define CONF 0.01f
#define NMSTHR 0.45f

// correctly-rounded fp32 exp via double (closest match to np.exp float32)
__device__ __forceinline__ float fexp_cr(float x) {
    return (float)exp((double)x);
}

// ---------------------------------------------------------------------------
// Kernel A: softmax over C=81 per (b,n) row; writes scores [B,N,C] and
// optionally the transposed foreground scores fg [B, C-1, N] into workspace.
// Sum mirrors numpy's pairwise_sum (8 accumulators) in fp32.
// ---------------------------------------------------------------------------
__global__ __launch_bounds__(256) void softmax_kernel(const float* __restrict__ logits,
                                                      float* __restrict__ scores,
                                                      float* __restrict__ fg, int use_fg) {
#pragma clang fp contract(off)
    int row = blockIdx.x * 256 + threadIdx.x;
    if (row >= BB * NN) return;
    const float* x = logits + (size_t)row * CC;

    float m = x[0];
    for (int c = 1; c < CC; ++c) m = fmaxf(m, x[c]);

    // numpy pairwise-style fp32 sum of exp(x - m), n = 81
    float r[8];
#pragma unroll
    for (int j = 0; j < 8; ++j) r[j] = expf(x[j] - m);
    for (int i = 8; i < 80; i += 8) {
#pragma unroll
        for (int j = 0; j < 8; ++j) r[j] += expf(x[i + j] - m);
    }
    float res = ((r[0] + r[1]) + (r[2] + r[3])) + ((r[4] + r[5]) + (r[6] + r[7]));
    res += expf(x[80] - m);

    int b = row / NN;
    int n = row - b * NN;
    float* srow = scores + (size_t)row * CC;
    for (int c = 0; c < CC; ++c) {
        float sc = expf(x[c] - m) / res;
        srow[c] = sc;
        if (use_fg && c > 0) {
            fg[((size_t)(b * CM1 + (c - 1))) * NN + n] = sc;
        }
    }
}

// ---------------------------------------------------------------------------
// Kernel B: decode boxes for all (b, n). Mirrors reference op order exactly.
// ---------------------------------------------------------------------------
__global__ __launch_bounds__(256) void decode_kernel(const float* __restrict__ loc,
                                                     const float* __restrict__ priors,
                                                     float* __restrict__ boxes) {
#pragma clang fp contract(off)
    int row = blockIdx.x * 256 + threadIdx.x;
    if (row >= BB * NN) return;
    int n = row % NN;
    float4 L = ((const float4*)loc)[row];
    float4 P = ((const float4*)priors)[n];
    float cx = (L.x * 0.1f) * P.z + P.x;
    float cy = (L.y * 0.1f) * P.w + P.y;
    float w  = fexp_cr(L.z * 0.2f) * P.z;
    float h  = fexp_cr(L.w * 0.2f) * P.w;
    float4 o;
    o.x = cx - w * 0.5f;   // wh/2 == wh*0.5f exactly
    o.y = cy - h * 0.5f;
    o.z = cx + w * 0.5f;
    o.w = cy + h * 0.5f;
    ((float4*)boxes)[row] = o;
}

// ---------------------------------------------------------------------------
// Kernel C: per (b, c) block — exact top-100 via radix-select on float bits,
// stable-sorted (value desc, index asc), then greedy NMS, then outputs.
// ---------------------------------------------------------------------------
__global__ __launch_bounds__(256) void topk_nms_kernel(
    const float* __restrict__ scores, const float* __restrict__ fg, int use_fg,
    const float* __restrict__ boxes,
    float* __restrict__ nms_scores, float* __restrict__ nms_boxes,
    float* __restrict__ keep_out)
{
#pragma clang fp contract(off)
    const int blk = blockIdx.x;        // b*80 + c
    const int b = blk / CM1;
    const int c = blk - b * CM1;
    const int tid = threadIdx.x;

    __shared__ unsigned hist[4096];
    __shared__ unsigned partial[256];
    __shared__ unsigned long long cand[CAP];
    __shared__ unsigned scnt;
    __shared__ unsigned s_T;
    __shared__ int s_b1, s_above, s_refine;
    __shared__ float sbx[KK][4];
    __shared__ float sarea[KK];
    __shared__ float sscore[KK];
    __shared__ int skeep[KK];

    const float* src;
    size_t stride;
    if (use_fg) { src = fg + ((size_t)(b * CM1 + c)) * NN; stride = 1; }
    else        { src = scores + ((size_t)b * NN) * CC + (c + 1); stride = CC; }

    // ---- pass 1: histogram on top 12 bits (values are positive floats) ----
    for (int i = tid; i < 4096; i += 256) hist[i] = 0u;
    __syncthreads();
    for (int n = tid; n < NN; n += 256) {
        unsigned bits = __float_as_uint(src[(size_t)n * stride]);
        atomicAdd(&hist[bits >> 20], 1u);
    }
    __syncthreads();
    unsigned psum = 0;
    for (int j = 0; j < 16; ++j) psum += hist[tid * 16 + j];
    partial[tid] = psum;
    __syncthreads();
    if (tid == 0) {
        unsigned acc = 0; int b1 = 0;
        for (int t = 255; t >= 0; --t) {
            if (acc + partial[t] >= (unsigned)KK) {
                for (int bin = t * 16 + 15; ; --bin) {
                    if (acc + hist[bin] >= (unsigned)KK) { b1 = bin; break; }
                    acc += hist[bin];
                }
                break;
            }
            acc += partial[t];
        }
        s_b1 = b1;
        s_above = (int)acc;                       // strictly above bin b1
        s_refine = (acc + hist[b1] > CAP) ? 1 : 0;
        s_T = ((unsigned)b1) << 20;
    }
    __syncthreads();

    // ---- optional refine on bits [19:8] if bin too dense ----
    if (s_refine) {
        int b1 = s_b1;
        for (int i = tid; i < 4096; i += 256) hist[i] = 0u;
        __syncthreads();
        for (int n = tid; n < NN; n += 256) {
            unsigned bits = __float_as_uint(src[(size_t)n * stride]);
            if ((int)(bits >> 20) == b1) atomicAdd(&hist[(bits >> 8) & 0xFFFu], 1u);
        }
        __syncthreads();
        psum = 0;
        for (int j = 0; j < 16; ++j) psum += hist[tid * 16 + j];
        partial[tid] = psum;
        __syncthreads();
        if (tid == 0) {
            int K2 = KK - s_above;
            unsigned acc = 0; int b2 = 0;
            for (int t = 255; t >= 0; --t) {
                if ((int)(acc + partial[t]) >= K2) {
                    for (int bin = t * 16 + 15; ; --bin) {
                        if ((int)(acc + hist[bin]) >= K2) { b2 = bin; break; }
                        acc += hist[bin];
                    }
                    break;
                }
                acc += partial[t];
            }
            s_T = (((unsigned)s_b1) << 20) | (((unsigned)b2) << 8);
        }
        __syncthreads();
    }

    // ---- collect candidates >= T ----
    if (tid == 0) scnt = 0u;
    __syncthreads();
    unsigned T = s_T;
    for (int n = tid; n < NN; n += 256) {
        unsigned bits = __float_as_uint(src[(size_t)n * stride]);
        if (bits >= T) {
            unsigned pos = atomicAdd(&scnt, 1u);
            if (pos < CAP) {
                cand[pos] = (((unsigned long long)bits) << 32)
                          | (unsigned)(0xFFFFFFFFu - (unsigned)n);
            }
        }
    }
    __syncthreads();
    unsigned cnt = scnt; if (cnt > CAP) cnt = CAP;
    for (int i = tid; i < CAP; i += 256) {
        if ((unsigned)i >= cnt) cand[i] = 0ull;
    }
    __syncthreads();

    // ---- bitonic sort, descending, CAP=512 elements, 256 threads ----
    for (unsigned k = 2; k <= CAP; k <<= 1) {
        for (unsigned j = k >> 1; j > 0; j >>= 1) {
            for (unsigned e = tid; e < CAP; e += 256) {
                unsigned ixj = e ^ j;
                if (ixj > e) {
                    unsigned long long a = cand[e], bb2 = cand[ixj];
                    bool desc = ((e & k) == 0);
                    if (desc ? (a < bb2) : (a > bb2)) { cand[e] = bb2; cand[ixj] = a; }
                }
            }
            __syncthreads();
        }
    }

    // ---- extract top-100, gather decoded boxes ----
    if (tid < KK) {
        unsigned long long key = cand[tid];
        unsigned bits = (unsigned)(key >> 32);
        unsigned n = 0xFFFFFFFFu - (unsigned)(key & 0xFFFFFFFFu);
        float s = __uint_as_float(bits);
        sscore[tid] = s;
        skeep[tid] = (s > CONF) ? 1 : 0;
        float4 bx = ((const float4*)boxes)[(size_t)b * NN + n];
        sbx[tid][0] = bx.x; sbx[tid][1] = bx.y; sbx[tid][2] = bx.z; sbx[tid][3] = bx.w;
        sarea[tid] = fmaxf(bx.z - bx.x, 0.f) * fmaxf(bx.w - bx.y, 0.f);
    }
    __syncthreads();

    // ---- greedy NMS (reference semantics: only kept boxes suppress) ----
    for (int i = 0; i < KK - 1; ++i) {
        if (skeep[i]) {
            int j = i + 1 + tid;
            if (j < KK) {
                float xx1 = fmaxf(sbx[i][0], sbx[j][0]);
                float yy1 = fmaxf(sbx[i][1], sbx[j][1]);
                float xx2 = fminf(sbx[i][2], sbx[j][2]);
                float yy2 = fminf(sbx[i][3], sbx[j][3]);
                float w = fmaxf(xx2 - xx1, 0.f);
                float h = fmaxf(yy2 - yy1, 0.f);
                float inter = w * h;
                float den = ((sarea[i] + sarea[j]) - inter) + 1e-8f;
                if (inter / den > NMSTHR) skeep[j] = 0;
            }
        }
        __syncthreads();
    }

    // ---- outputs ----
    if (tid < KK) {
        int kf = skeep[tid];
        size_t oidx = (size_t)blk * KK + tid;
        nms_scores[oidx] = kf ? sscore[tid] : 0.f;
        keep_out[oidx]   = kf ? 1.f : 0.f;
        float4 ob;
        ob.x = kf ? sbx[tid][0] : 0.f;
        ob.y = kf ? sbx[tid][1] : 0.f;
        ob.z = kf ? sbx[tid][2] : 0.f;
        ob.w = kf ? sbx[tid][3] : 0.f;
        ((float4*)nms_boxes)[oidx] = ob;
    }
}

extern "C" void kernel_launch(void* const* d_in, const int* in_sizes, int n_in,
                              void* d_out, int out_size, void* d_ws, size_t ws_size,
                              hipStream_t stream) {
    const float* logits = (const float*)d_in[0];
    const float* bbox   = (const float*)d_in[1];
    const float* priors = (const float*)d_in[2];

    float* out = (float*)d_out;
    float* scores     = out;
    float* boxes      = scores + (size_t)BB * NN * CC;
    float* nms_scores = boxes + (size_t)BB * NN * 4;
    float* nms_boxes  = nms_scores + (size_t)BB * CM1 * KK;
    float* keep_out   = nms_boxes + (size_t)BB * CM1 * KK * 4;

    size_t fg_bytes = (size_t)BB * CM1 * NN * sizeof(float);
    int use_fg = (ws_size >= fg_bytes) ? 1 : 0;
    float* fg = (float*)d_ws;

    int rows = BB * NN;
    int blocksA = (rows + 255) / 256;
    softmax_kernel<<<blocksA, 256, 0, stream>>>(logits, scores, fg, use_fg);
    decode_kernel<<<blocksA, 256, 0, stream>>>(bbox, priors, boxes);
    topk_nms_kernel<<<BB * CM1, 256, 0, stream>>>(scores, fg, use_fg, boxes,
                                                  nms_scores, nms_boxes, keep_out);
}